// Round 3
// 87.947 us; speedup vs baseline: 1.0008x; 1.0008x over previous
//
#include <hip/hip_runtime.h>

// N=4096 rows, D=128 in-dim, P=128 pe-dim, H=256 hidden.
// out: (N, 129) fp32, col 0 = ones, col j+1 = x[:,j] * (1 + g_j)
//
//   base[n][h] = sum_i x[n][i]*W1[i][h] + b1[h]          (kernel 1 -> fp32 d_ws)
//   g = sum_h relu(base[n][h] + W1[128+j][h] - x[n][j]*W1[j][h]) * W2[h] + b2
//   out[n][1+j] = x[n][j] * (1 + g)
//
// Round-2 lesson: fp16 staged through d_ws across kernels read poison
// (error signatures matched poisoned bb / poisoned wa,wp exactly). This
// version keeps kernel 1 byte-identical to the proven fp32 variant and makes
// kernel 2 self-contained: it converts its 16 needed W1 rows to fp16 in LDS
// (one-time 8 KB) and bb/W2 to fp16 in registers. Inner loop: per 16 h-elems
// 8 x { v_pk_add_f16, v_pk_fma_f16, v_pk_max_f16, v_dot2_f32_f16 } with
// all-VGPR operands (wa/wp via wave-uniform ds_read broadcast).

#define NROWS 4096
#define DIN   128
#define HDIM  256
#define JCH   8

typedef _Float16 h2 __attribute__((ext_vector_type(2)));

static __device__ __forceinline__ h2 mk_h2(float a, float b) {
    h2 r; r[0] = (_Float16)a; r[1] = (_Float16)b; return r;
}

// ---------------- Kernel 1: baseb = x @ W1[:128] + b1 (fp32, proven) -----
// grid (128,4), block 256. Tile 32 rows x 64 h, K=128 of x transposed in LDS.
__global__ __launch_bounds__(256) void nimo_base(
    const float* __restrict__ x, const float* __restrict__ W1,
    const float* __restrict__ b1, float* __restrict__ baseb)
{
    __shared__ float xs[DIN * 36];
    const int tid  = threadIdx.x;
    const int row0 = blockIdx.x * 32;
    const int h0   = blockIdx.y * 64;

    {
        const int bidx = tid * 16;
        const int r = bidx >> 7;
        const int c = bidx & 127;
        #pragma unroll
        for (int u = 0; u < 4; ++u) {
            const float4 v = *(const float4*)(x + (size_t)(row0 + r) * DIN + c + u * 4);
            xs[(c + u * 4 + 0) * 36 + r] = v.x;
            xs[(c + u * 4 + 1) * 36 + r] = v.y;
            xs[(c + u * 4 + 2) * 36 + r] = v.z;
            xs[(c + u * 4 + 3) * 36 + r] = v.w;
        }
    }
    __syncthreads();

    const int tx = tid & 31;
    const int ty = tid >> 5;
    const float* __restrict__ wcol = W1 + h0 + tx * 2;

    float2 acc[4];
    #pragma unroll
    for (int u = 0; u < 4; ++u) { acc[u].x = 0.f; acc[u].y = 0.f; }

    #pragma unroll 8
    for (int k = 0; k < DIN; ++k) {
        const float2 w  = *(const float2*)(wcol + (size_t)k * HDIM);
        const float4 xv = *(const float4*)(&xs[k * 36 + ty * 4]);
        acc[0].x = fmaf(xv.x, w.x, acc[0].x); acc[0].y = fmaf(xv.x, w.y, acc[0].y);
        acc[1].x = fmaf(xv.y, w.x, acc[1].x); acc[1].y = fmaf(xv.y, w.y, acc[1].y);
        acc[2].x = fmaf(xv.z, w.x, acc[2].x); acc[2].y = fmaf(xv.z, w.y, acc[2].y);
        acc[3].x = fmaf(xv.w, w.x, acc[3].x); acc[3].y = fmaf(xv.w, w.y, acc[3].y);
    }

    const float2 bv = *(const float2*)(b1 + h0 + tx * 2);
    #pragma unroll
    for (int u = 0; u < 4; ++u) {
        float2 o; o.x = acc[u].x + bv.x; o.y = acc[u].y + bv.y;
        *(float2*)(baseb + (size_t)(row0 + ty * 4 + u) * HDIM + h0 + tx * 2) = o;
    }
}

// ---------------- Kernel 2: masked-MLP evaluation (packed fp16) ----------
// grid (64, 16), block 1024 = 16 waves. Wave q owns h-chunk [q*16, q*16+16);
// lane = row (r = tid&63). bb/W2 converted to fp16 in registers (constant
// index only -> no scratch). W1 rows j0..j0+7 and 128+j0..+7 converted to
// fp16 in LDS once per block; inner loop reads them with wave-uniform
// ds_read_b128 (broadcast, conflict-free). 16-way h-partials combined once
// via LDS. LDS total ~44 KB -> 2 blocks/CU, 32 waves/CU.
__global__ __launch_bounds__(1024, 8) void nimo_main(
    const float* __restrict__ x, const float* __restrict__ W1,
    const float* __restrict__ W2, const float* __restrict__ b2,
    const float* __restrict__ baseb, float* __restrict__ out)
{
    __shared__ float xs[64][JCH + 1];      // x[row0+r][j0+jj]
    __shared__ float part[16][JCH][66];    // per-wave h-partials
    __shared__ __align__(16) _Float16 w1s[16][HDIM];  // rows 0..7: W1[j0+rl], 8..15: W1[128+j0+rl]

    const int tid  = threadIdx.x;
    const int r    = tid & 63;
    const int q    = tid >> 6;             // wave id 0..15
    const int row0 = blockIdx.x * 64;
    const int row  = row0 + r;
    const int j0   = blockIdx.y * JCH;
    const int h0   = q * 16;

    // stage x tile (64 rows x JCH cols)
    if (tid < 512) {
        const int xr = tid >> 3;
        const int xc = tid & 7;
        xs[xr][xc] = x[(size_t)(row0 + xr) * DIN + j0 + xc];
    }

    // stage fp16 W1 tile: 16 rows x 256 cols; each thread converts one
    // col-pair in one wa-row and the matching wp-row.
    {
        const int rl = tid >> 7;           // 0..7
        const int c2 = (tid & 127) * 2;    // 0,2,...,254
        const float* wr = W1 + (size_t)(j0 + rl) * HDIM + c2;
        *(h2*)&w1s[rl][c2] = mk_h2(wr[0], wr[1]);
        const float* wr2 = W1 + (size_t)(DIN + j0 + rl) * HDIM + c2;
        *(h2*)&w1s[8 + rl][c2] = mk_h2(wr2[0], wr2[1]);
    }

    // per-lane resident data (constant-index only -> stays in VGPRs)
    h2 bbh[8], w2h[8];
    {
        const float4* bp = (const float4*)(baseb + (size_t)row * HDIM + h0);
        const float4 v0 = bp[0], v1 = bp[1], v2 = bp[2], v3 = bp[3];
        bbh[0] = mk_h2(v0.x, v0.y); bbh[1] = mk_h2(v0.z, v0.w);
        bbh[2] = mk_h2(v1.x, v1.y); bbh[3] = mk_h2(v1.z, v1.w);
        bbh[4] = mk_h2(v2.x, v2.y); bbh[5] = mk_h2(v2.z, v2.w);
        bbh[6] = mk_h2(v3.x, v3.y); bbh[7] = mk_h2(v3.z, v3.w);
        const float4* wp2 = (const float4*)(W2 + h0);
        const float4 u0 = wp2[0], u1 = wp2[1], u2 = wp2[2], u3 = wp2[3];
        w2h[0] = mk_h2(u0.x, u0.y); w2h[1] = mk_h2(u0.z, u0.w);
        w2h[2] = mk_h2(u1.x, u1.y); w2h[3] = mk_h2(u1.z, u1.w);
        w2h[4] = mk_h2(u2.x, u2.y); w2h[5] = mk_h2(u2.z, u2.w);
        w2h[6] = mk_h2(u3.x, u3.y); w2h[7] = mk_h2(u3.z, u3.w);
    }
    __syncthreads();

    h2 z2; z2[0] = (_Float16)0.f; z2[1] = (_Float16)0.f;

    for (int jj = 0; jj < JCH; ++jj) {
        const float xj = xs[r][jj];
        const _Float16 nv = (_Float16)(-xj);
        h2 nx2; nx2[0] = nv; nx2[1] = nv;

        // wave-uniform LDS broadcast reads: 16 halves of wa-row and wp-row
        const uint4 wa_lo = *(const uint4*)&w1s[jj][h0];
        const uint4 wa_hi = *(const uint4*)&w1s[jj][h0 + 8];
        const uint4 wp_lo = *(const uint4*)&w1s[8 + jj][h0];
        const uint4 wp_hi = *(const uint4*)&w1s[8 + jj][h0 + 8];

        float acc = 0.f;
        #define STEP(P, WAU, WPU) { \
            const h2 wa = __builtin_bit_cast(h2, WAU); \
            const h2 wp = __builtin_bit_cast(h2, WPU); \
            h2 t = bbh[P] + wp;                      /* v_pk_add_f16 */ \
            t = nx2 * wa + t;                        /* v_pk_fma_f16 */ \
            t = __builtin_elementwise_max(t, z2);    /* v_pk_max_f16 */ \
            acc = __builtin_amdgcn_fdot2(t, w2h[P], acc, false); }
        STEP(0, wa_lo.x, wp_lo.x) STEP(1, wa_lo.y, wp_lo.y)
        STEP(2, wa_lo.z, wp_lo.z) STEP(3, wa_lo.w, wp_lo.w)
        STEP(4, wa_hi.x, wp_hi.x) STEP(5, wa_hi.y, wp_hi.y)
        STEP(6, wa_hi.z, wp_hi.z) STEP(7, wa_hi.w, wp_hi.w)
        #undef STEP

        part[q][jj][r] = acc;                 // lane=r consecutive: conflict-free
    }
    __syncthreads();

    const float b2s = b2[0];
    if (blockIdx.y == 0 && tid < 64) out[(size_t)(row0 + tid) * 129] = 1.0f;

    if (tid < 512) {
        const int rr = tid >> 3;              // 0..63
        const int jj = tid & 7;               // 0..7
        float g = 0.f;
        #pragma unroll
        for (int qq = 0; qq < 16; ++qq) g += part[qq][jj][rr];
        const float xv = xs[rr][jj];
        out[(size_t)(row0 + rr) * 129 + 1 + j0 + jj] = xv * (1.0f + g + b2s);
    }
}

extern "C" void kernel_launch(void* const* d_in, const int* in_sizes, int n_in,
                              void* d_out, int out_size, void* d_ws, size_t ws_size,
                              hipStream_t stream) {
    const float* x  = (const float*)d_in[0];   // 4096*128
    const float* W1 = (const float*)d_in[1];   // 256*256
    const float* b1 = (const float*)d_in[2];   // 256
    const float* W2 = (const float*)d_in[3];   // 256
    const float* b2 = (const float*)d_in[4];   // 1
    float* out = (float*)d_out;                // 4096*129
    float* baseb = (float*)d_ws;               // 4096*256 fp32 = 4 MB scratch

    nimo_base<<<dim3(NROWS / 32, HDIM / 64), 256, 0, stream>>>(x, W1, b1, baseb);
    nimo_main<<<dim3(NROWS / 64, DIN / JCH), 1024, 0, stream>>>(x, W1, W2, b2, baseb, out);
}